// Round 7
// baseline (169.315 us; speedup 1.0000x reference)
//
#include <hip/hip_runtime.h>
#include <math.h>

// Problem constants (match reference)
#define NB 16
#define NC 512
#define NL 8192
#define KW 7

// Chunked pipeline: process CHUNKB batches fully (pool -> conv -> apply)
// before moving on, so the apply-pass re-read of x hits a 128MB window that
// is guaranteed Infinity-Cache resident (L3=256MB; x whole is exactly 256MB
// -- that was round 6's marginal-retention failure).
#define CHUNKB 8
#define SLABS 64            // channel slabs per batch
#define SCH (NC / SLABS)    // 8 rows per slab
#define NF4 (NL / 4)        // 2048 float4 per row
#define FPT (NF4 / 256)     // 8 float4-columns per thread

typedef float vf4 __attribute__((ext_vector_type(4)));

// ---------------------------------------------------------------------------
// K1: per-slab pooling partials. Block (256 thr) = (b, slab): reads 8 rows x
// 32KB in pure layout order; thread owns f4-cols tid+256*i, accumulates
// max/sum over the 8 rows in registers. 512 blocks/chunk => 2 blocks/CU.
// part[(b*SLABS+s)*2 + {0=max,1=sum}][NL]
// ---------------------------------------------------------------------------
__global__ __launch_bounds__(256) void k1_pool(
    const float* __restrict__ x, float* __restrict__ part, int b0) {
    const int blk = blockIdx.x;
    const int b   = b0 + (blk >> 6);
    const int s   = blk & (SLABS - 1);
    const int tid = threadIdx.x;

    const float* px = x + ((size_t)b * NC + (size_t)s * SCH) * NL;

    vf4 mx[FPT], sm[FPT];
#pragma unroll
    for (int i = 0; i < FPT; ++i) {
        vf4 v = *(const vf4*)(px + 4 * (tid + 256 * i));
        mx[i] = v; sm[i] = v;
    }
#pragma unroll 2
    for (int r = 1; r < SCH; ++r) {
        const float* pr = px + (size_t)r * NL;
#pragma unroll
        for (int i = 0; i < FPT; ++i) {
            vf4 v = *(const vf4*)(pr + 4 * (tid + 256 * i));
            mx[i].x = fmaxf(mx[i].x, v.x); sm[i].x += v.x;
            mx[i].y = fmaxf(mx[i].y, v.y); sm[i].y += v.y;
            mx[i].z = fmaxf(mx[i].z, v.z); sm[i].z += v.z;
            mx[i].w = fmaxf(mx[i].w, v.w); sm[i].w += v.w;
        }
    }
    float* pm = part + (((size_t)b * SLABS + s) * 2 + 0) * NL;
    float* ps = part + (((size_t)b * SLABS + s) * 2 + 1) * NL;
#pragma unroll
    for (int i = 0; i < FPT; ++i) {
        *(vf4*)(pm + 4 * (tid + 256 * i)) = mx[i];
        *(vf4*)(ps + 4 * (tid + 256 * i)) = sm[i];
    }
}

// ---------------------------------------------------------------------------
// K2: finish pooling (reduce 64 slabs), 7-tap conv (cross-correlation,
// zero-padded) + sigmoid -> attn[b][l]. part is L3-resident (just written).
// ---------------------------------------------------------------------------
#define K2OUT 250
#define K2NT ((NL + K2OUT - 1) / K2OUT)   // 33
__global__ __launch_bounds__(256) void k2_conv(
    const float* __restrict__ part, const float* __restrict__ w,
    float* __restrict__ attn, int b0) {
    __shared__ float pm[256], pa[256], wl[2 * KW];
    const int b    = b0 + blockIdx.x / K2NT;
    const int t    = blockIdx.x % K2NT;
    const int base = t * K2OUT;
    const int tid  = threadIdx.x;
    if (tid < 2 * KW) wl[tid] = w[tid];

    const int pc = base - 3 + tid;               // pooled column this thread computes
    if (pc >= 0 && pc < NL) {
        float m = -INFINITY, sm = 0.0f;
#pragma unroll 8
        for (int s = 0; s < SLABS; ++s) {
            m  = fmaxf(m, part[(((size_t)b * SLABS + s) * 2 + 0) * NL + pc]);
            sm += part[(((size_t)b * SLABS + s) * 2 + 1) * NL + pc];
        }
        pm[tid] = m;
        pa[tid] = sm * (1.0f / (float)NC);
    } else {
        pm[tid] = 0.0f;                          // conv zero-padding
        pa[tid] = 0.0f;
    }
    __syncthreads();

    const int l = base + tid;
    if (tid < K2OUT && l < NL) {
        float logit = 0.0f;
#pragma unroll
        for (int k = 0; k < KW; ++k) {
            logit = fmaf(pm[tid + k], wl[k],      logit);
            logit = fmaf(pa[tid + k], wl[KW + k], logit);
        }
        attn[(size_t)b * NL + l] = 1.0f / (1.0f + expf(-logit));
    }
}

// ---------------------------------------------------------------------------
// K3: out = attn[b,l] * x for this chunk. x chunk (128MB) is L3-resident
// (K1 just streamed it; nothing big has run since). NT stores keep the out
// stream from allocating in L3 and evicting the next chunk's reads.
// ---------------------------------------------------------------------------
__global__ __launch_bounds__(256) void k3_apply(
    const float* __restrict__ x, const float* __restrict__ attn,
    float* __restrict__ out, int b0) {
    const int blk = blockIdx.x;
    const int b   = b0 + (blk >> 6);
    const int s   = blk & (SLABS - 1);
    const int tid = threadIdx.x;

    const size_t base = ((size_t)b * NC + (size_t)s * SCH) * NL;
    const float* px = x + base;
    float*       po = out + base;

    vf4 at[FPT];
#pragma unroll
    for (int i = 0; i < FPT; ++i)
        at[i] = *(const vf4*)(attn + (size_t)b * NL + 4 * (tid + 256 * i));

#pragma unroll 2
    for (int r = 0; r < SCH; ++r) {
        const float* pr = px + (size_t)r * NL;
        float*       pw = po + (size_t)r * NL;
#pragma unroll
        for (int i = 0; i < FPT; ++i) {
            vf4 v = *(const vf4*)(pr + 4 * (tid + 256 * i));
            vf4 o;
            o.x = at[i].x * v.x;
            o.y = at[i].y * v.y;
            o.z = at[i].z * v.z;
            o.w = at[i].w * v.w;
            __builtin_nontemporal_store(o, (vf4*)(pw + 4 * (tid + 256 * i)));
        }
    }
}

extern "C" void kernel_launch(void* const* d_in, const int* in_sizes, int n_in,
                              void* d_out, int out_size, void* d_ws, size_t ws_size,
                              hipStream_t stream) {
    const float* x = (const float*)d_in[0];
    // d_in[1] = mask — intentionally unused (reference discards masked_fill).
    const float* w = (const float*)d_in[2];   // flat (1,2,7): [0..6]=max taps, [7..13]=avg taps
    float* out = (float*)d_out;

    float* part = (float*)d_ws;                          // 16*64*2*8192 f32 = 67MB
    float* attn = part + (size_t)NB * SLABS * 2 * NL;    // 16*8192 f32 = 512KB

    for (int chunk = 0; chunk < NB / CHUNKB; ++chunk) {
        const int b0 = chunk * CHUNKB;
        k1_pool<<<CHUNKB * SLABS, 256, 0, stream>>>(x, part, b0);        // 512 blocks
        k2_conv<<<CHUNKB * K2NT, 256, 0, stream>>>(part, w, attn, b0);   // 264 blocks
        k3_apply<<<CHUNKB * SLABS, 256, 0, stream>>>(x, attn, out, b0);  // 512 blocks
    }
}

// Round 9
// 152.753 us; speedup vs baseline: 1.1084x; 1.1084x over previous
//
#include <hip/hip_runtime.h>
#include <math.h>

// Problem constants (match reference)
#define NB 16
#define NC 512
#define NL 8192
#define KW 7
#define SLABS 16            // channel slabs (K1)
#define SCH (NC / SLABS)    // 32 channels per slab (K1)
#define SLABS3 32           // channel slabs (K3) -> 512 blocks = 2/CU
#define SCH3 (NC / SLABS3)  // 16 channels per slab (K3)

typedef float vf4 __attribute__((ext_vector_type(4)));

// ---------------------------------------------------------------------------
// K1: per-slab pooling partials. One block = (b, slab). The block reads its
// 32 rows x 32KB = 1MB region in PURE LAYOUT ORDER (1KB per wave-instruction,
// rows sequential). Normal loads (part/attn want L2/L3 residency for K2).
// Partials: part[(b*SLABS+s)*2 + {0=max,1=sum}][NL].
// ---------------------------------------------------------------------------
__global__ __launch_bounds__(1024) void k1_pool(
    const float* __restrict__ x, float* __restrict__ part) {
    const int blk = blockIdx.x;            // b*SLABS + s
    const int tid = threadIdx.x;

    const float* px = x + (size_t)blk * SCH * NL;

    vf4 v0 = *(const vf4*)(px + 4 * tid);
    vf4 v1 = *(const vf4*)(px + 4 * (tid + 1024));
    vf4 mx0 = v0, sm0 = v0, mx1 = v1, sm1 = v1;

#pragma unroll 4
    for (int c = 1; c < SCH; ++c) {
        const float* pr = px + (size_t)c * NL;
        vf4 a = *(const vf4*)(pr + 4 * tid);
        vf4 bq = *(const vf4*)(pr + 4 * (tid + 1024));
        mx0.x = fmaxf(mx0.x, a.x);  sm0.x += a.x;
        mx0.y = fmaxf(mx0.y, a.y);  sm0.y += a.y;
        mx0.z = fmaxf(mx0.z, a.z);  sm0.z += a.z;
        mx0.w = fmaxf(mx0.w, a.w);  sm0.w += a.w;
        mx1.x = fmaxf(mx1.x, bq.x); sm1.x += bq.x;
        mx1.y = fmaxf(mx1.y, bq.y); sm1.y += bq.y;
        mx1.z = fmaxf(mx1.z, bq.z); sm1.z += bq.z;
        mx1.w = fmaxf(mx1.w, bq.w); sm1.w += bq.w;
    }

    float* pm = part + ((size_t)blk * 2 + 0) * NL;
    float* ps = part + ((size_t)blk * 2 + 1) * NL;
    *(vf4*)(pm + 4 * tid)          = mx0;
    *(vf4*)(pm + 4 * (tid + 1024)) = mx1;
    *(vf4*)(ps + 4 * tid)          = sm0;
    *(vf4*)(ps + 4 * (tid + 1024)) = sm1;
}

// ---------------------------------------------------------------------------
// K2: finish pooling (reduce 16 slabs), 7-tap conv (cross-correlation,
// zero-padded) + sigmoid -> attn[b][l]. Tiny (17MB, mostly L2/L3-resident).
// ---------------------------------------------------------------------------
#define K2OUT 250
__global__ __launch_bounds__(256) void k2_conv(
    const float* __restrict__ part, const float* __restrict__ w,
    float* __restrict__ attn) {
    __shared__ float pm[256], pa[256], wl[2 * KW];
    const int nt   = (NL + K2OUT - 1) / K2OUT;   // 33
    const int b    = blockIdx.x / nt;
    const int t    = blockIdx.x - b * nt;
    const int base = t * K2OUT;
    const int tid  = threadIdx.x;
    if (tid < 2 * KW) wl[tid] = w[tid];

    const int pc = base - 3 + tid;               // pooled column this thread computes
    if (pc >= 0 && pc < NL) {
        float m = -INFINITY, sm = 0.0f;
#pragma unroll
        for (int s = 0; s < SLABS; ++s) {
            m  = fmaxf(m, part[(((size_t)b * SLABS + s) * 2 + 0) * NL + pc]);
            sm += part[(((size_t)b * SLABS + s) * 2 + 1) * NL + pc];
        }
        pm[tid] = m;
        pa[tid] = sm * (1.0f / (float)NC);
    } else {
        pm[tid] = 0.0f;                          // conv zero-padding
        pa[tid] = 0.0f;
    }
    __syncthreads();

    const int l = base + tid;
    if (tid < K2OUT && l < NL) {
        float logit = 0.0f;
#pragma unroll
        for (int k = 0; k < KW; ++k) {
            logit = fmaf(pm[tid + k], wl[k],      logit);
            logit = fmaf(pa[tid + k], wl[KW + k], logit);
        }
        attn[(size_t)b * NL + l] = 1.0f / (1.0f + expf(-logit));
    }
}

// ---------------------------------------------------------------------------
// K3: out = attn[b,l] * x. Mixed read+write stream. Round-9 deltas vs round 6:
//   (a) 512 blocks (16 rows/slab) = 2 blocks/CU = 32 waves/CU -> more TLP to
//       hide HBM read<->write turnaround (K3 ran 6.1 TB/s at 16 waves/CU);
//   (b) NON-TEMPORAL loads for x: single-use stream, don't allocate/churn
//       L2/L3 against the NT write stream.
// ---------------------------------------------------------------------------
__global__ __launch_bounds__(1024) void k3_apply(
    const float* __restrict__ x, const float* __restrict__ attn,
    float* __restrict__ out) {
    const int blk = blockIdx.x;            // b*SLABS3 + s
    const int b   = blk >> 5;
    const int tid = threadIdx.x;

    const size_t base = (size_t)blk * SCH3 * NL;
    const float* px = x + base;
    float*       po = out + base;

    const vf4 at0 = *(const vf4*)(attn + (size_t)b * NL + 4 * tid);
    const vf4 at1 = *(const vf4*)(attn + (size_t)b * NL + 4 * (tid + 1024));

#pragma unroll 4
    for (int c = 0; c < SCH3; ++c) {
        const float* pr = px + (size_t)c * NL;
        float*       pw = po + (size_t)c * NL;
        vf4 a  = __builtin_nontemporal_load((const vf4*)(pr + 4 * tid));
        vf4 bq = __builtin_nontemporal_load((const vf4*)(pr + 4 * (tid + 1024)));
        vf4 o0, o1;
        o0.x = at0.x * a.x;  o0.y = at0.y * a.y;
        o0.z = at0.z * a.z;  o0.w = at0.w * a.w;
        o1.x = at1.x * bq.x; o1.y = at1.y * bq.y;
        o1.z = at1.z * bq.z; o1.w = at1.w * bq.w;
        __builtin_nontemporal_store(o0, (vf4*)(pw + 4 * tid));
        __builtin_nontemporal_store(o1, (vf4*)(pw + 4 * (tid + 1024)));
    }
}

extern "C" void kernel_launch(void* const* d_in, const int* in_sizes, int n_in,
                              void* d_out, int out_size, void* d_ws, size_t ws_size,
                              hipStream_t stream) {
    const float* x = (const float*)d_in[0];
    // d_in[1] = mask — intentionally unused (reference discards masked_fill).
    const float* w = (const float*)d_in[2];   // flat (1,2,7): [0..6]=max taps, [7..13]=avg taps
    float* out = (float*)d_out;

    float* part = (float*)d_ws;                          // 16*16*2*8192 f32 = 16MB
    float* attn = part + (size_t)NB * SLABS * 2 * NL;    // 16*8192 f32 = 512KB

    k1_pool<<<NB * SLABS, 1024, 0, stream>>>(x, part);                            // 256 blocks
    k2_conv<<<NB * ((NL + K2OUT - 1) / K2OUT), 256, 0, stream>>>(part, w, attn);  // 528 blocks
    k3_apply<<<NB * SLABS3, 1024, 0, stream>>>(x, attn, out);                     // 512 blocks
}

// Round 10
// 142.459 us; speedup vs baseline: 1.1885x; 1.0723x over previous
//
#include <hip/hip_runtime.h>
#include <math.h>

// Problem constants (match reference)
#define NB 16
#define NC 512
#define NL 8192
#define KW 7
#define SLABS 16            // channel slabs (K1)
#define SCH (NC / SLABS)    // 32 channels per slab (K1)
#define SLABS3 32           // channel slabs (K3) -> 512 blocks = 2/CU
#define SCH3 (NC / SLABS3)  // 16 channels per slab (K3)

typedef float vf4 __attribute__((ext_vector_type(4)));

// ---------------------------------------------------------------------------
// K1: per-slab pooling partials. One block = (b, slab). The block reads its
// 32 rows x 32KB = 1MB region in PURE LAYOUT ORDER (1KB per wave-instruction,
// rows sequential). Normal loads.
// Partials: part[(b*SLABS+s)*2 + {0=max,1=sum}][NL].
// ---------------------------------------------------------------------------
__global__ __launch_bounds__(1024) void k1_pool(
    const float* __restrict__ x, float* __restrict__ part) {
    const int blk = blockIdx.x;            // b*SLABS + s
    const int tid = threadIdx.x;

    const float* px = x + (size_t)blk * SCH * NL;

    vf4 v0 = *(const vf4*)(px + 4 * tid);
    vf4 v1 = *(const vf4*)(px + 4 * (tid + 1024));
    vf4 mx0 = v0, sm0 = v0, mx1 = v1, sm1 = v1;

#pragma unroll 4
    for (int c = 1; c < SCH; ++c) {
        const float* pr = px + (size_t)c * NL;
        vf4 a = *(const vf4*)(pr + 4 * tid);
        vf4 bq = *(const vf4*)(pr + 4 * (tid + 1024));
        mx0.x = fmaxf(mx0.x, a.x);  sm0.x += a.x;
        mx0.y = fmaxf(mx0.y, a.y);  sm0.y += a.y;
        mx0.z = fmaxf(mx0.z, a.z);  sm0.z += a.z;
        mx0.w = fmaxf(mx0.w, a.w);  sm0.w += a.w;
        mx1.x = fmaxf(mx1.x, bq.x); sm1.x += bq.x;
        mx1.y = fmaxf(mx1.y, bq.y); sm1.y += bq.y;
        mx1.z = fmaxf(mx1.z, bq.z); sm1.z += bq.z;
        mx1.w = fmaxf(mx1.w, bq.w); sm1.w += bq.w;
    }

    float* pm = part + ((size_t)blk * 2 + 0) * NL;
    float* ps = part + ((size_t)blk * 2 + 1) * NL;
    *(vf4*)(pm + 4 * tid)          = mx0;
    *(vf4*)(pm + 4 * (tid + 1024)) = mx1;
    *(vf4*)(ps + 4 * tid)          = sm0;
    *(vf4*)(ps + 4 * (tid + 1024)) = sm1;
}

// ---------------------------------------------------------------------------
// K2: finish pooling (reduce 16 slabs), 7-tap conv (cross-correlation,
// zero-padded) + sigmoid -> attn[b][l]. Tiny (17MB, mostly L2/L3-resident).
// ---------------------------------------------------------------------------
#define K2OUT 250
__global__ __launch_bounds__(256) void k2_conv(
    const float* __restrict__ part, const float* __restrict__ w,
    float* __restrict__ attn) {
    __shared__ float pm[256], pa[256], wl[2 * KW];
    const int nt   = (NL + K2OUT - 1) / K2OUT;   // 33
    const int b    = blockIdx.x / nt;
    const int t    = blockIdx.x - b * nt;
    const int base = t * K2OUT;
    const int tid  = threadIdx.x;
    if (tid < 2 * KW) wl[tid] = w[tid];

    const int pc = base - 3 + tid;               // pooled column this thread computes
    if (pc >= 0 && pc < NL) {
        float m = -INFINITY, sm = 0.0f;
#pragma unroll
        for (int s = 0; s < SLABS; ++s) {
            m  = fmaxf(m, part[(((size_t)b * SLABS + s) * 2 + 0) * NL + pc]);
            sm += part[(((size_t)b * SLABS + s) * 2 + 1) * NL + pc];
        }
        pm[tid] = m;
        pa[tid] = sm * (1.0f / (float)NC);
    } else {
        pm[tid] = 0.0f;                          // conv zero-padding
        pa[tid] = 0.0f;
    }
    __syncthreads();

    const int l = base + tid;
    if (tid < K2OUT && l < NL) {
        float logit = 0.0f;
#pragma unroll
        for (int k = 0; k < KW; ++k) {
            logit = fmaf(pm[tid + k], wl[k],      logit);
            logit = fmaf(pa[tid + k], wl[KW + k], logit);
        }
        attn[(size_t)b * NL + l] = 1.0f / (1.0f + expf(-logit));
    }
}

// ---------------------------------------------------------------------------
// K3: out = attn[b,l] * x. Mixed read+write stream.
// Round-10 A/B vs round 9: keep the 2-blocks/CU occupancy (512 blocks,
// 16-row slabs) but REVERT to normal caching loads (round 9's NT loads
// regressed K3 by ~9us: they bypass L2/L3 allocation, killing the residual
// cache hits round 6 was getting). NT stores kept (round 6's proven win).
// ---------------------------------------------------------------------------
__global__ __launch_bounds__(1024) void k3_apply(
    const float* __restrict__ x, const float* __restrict__ attn,
    float* __restrict__ out) {
    const int blk = blockIdx.x;            // b*SLABS3 + s
    const int b   = blk >> 5;
    const int tid = threadIdx.x;

    const size_t base = (size_t)blk * SCH3 * NL;
    const float* px = x + base;
    float*       po = out + base;

    const vf4 at0 = *(const vf4*)(attn + (size_t)b * NL + 4 * tid);
    const vf4 at1 = *(const vf4*)(attn + (size_t)b * NL + 4 * (tid + 1024));

#pragma unroll 4
    for (int c = 0; c < SCH3; ++c) {
        const float* pr = px + (size_t)c * NL;
        float*       pw = po + (size_t)c * NL;
        vf4 a  = *(const vf4*)(pr + 4 * tid);
        vf4 bq = *(const vf4*)(pr + 4 * (tid + 1024));
        vf4 o0, o1;
        o0.x = at0.x * a.x;  o0.y = at0.y * a.y;
        o0.z = at0.z * a.z;  o0.w = at0.w * a.w;
        o1.x = at1.x * bq.x; o1.y = at1.y * bq.y;
        o1.z = at1.z * bq.z; o1.w = at1.w * bq.w;
        __builtin_nontemporal_store(o0, (vf4*)(pw + 4 * tid));
        __builtin_nontemporal_store(o1, (vf4*)(pw + 4 * (tid + 1024)));
    }
}

extern "C" void kernel_launch(void* const* d_in, const int* in_sizes, int n_in,
                              void* d_out, int out_size, void* d_ws, size_t ws_size,
                              hipStream_t stream) {
    const float* x = (const float*)d_in[0];
    // d_in[1] = mask — intentionally unused (reference discards masked_fill).
    const float* w = (const float*)d_in[2];   // flat (1,2,7): [0..6]=max taps, [7..13]=avg taps
    float* out = (float*)d_out;

    float* part = (float*)d_ws;                          // 16*16*2*8192 f32 = 16MB
    float* attn = part + (size_t)NB * SLABS * 2 * NL;    // 16*8192 f32 = 512KB

    k1_pool<<<NB * SLABS, 1024, 0, stream>>>(x, part);                            // 256 blocks
    k2_conv<<<NB * ((NL + K2OUT - 1) / K2OUT), 256, 0, stream>>>(part, w, attn);  // 528 blocks
    k3_apply<<<NB * SLABS3, 1024, 0, stream>>>(x, attn, out);                     // 512 blocks
}